// Round 1
// baseline (132.457 us; speedup 1.0000x reference)
//
#include <hip/hip_runtime.h>
#include <cstdint>
#include <cstddef>

// Problem constants (F, H, D, A, B) = (500, 2000, 64, 64, 4096)
#define F_N 500
#define H_N 2000
#define JN  2500   // F + H
#define D_N 64
#define A_N 64
#define B_N 4096

// ---------------------------------------------------------------------------
// Kernel 1: pre_f[i][a] = feat_emb[i,:] @ W1[:,a] + bw[a]      (i in [0,500))
//           pre_w[j][a] = full[j,:]     @ W2[:,a]              (j in [0,2500))
// full[j] = j < 500 ? feat_emb[j] : hid_emb[j-500]
// One wave per output row; lane = a. 750 blocks x 256 threads (4 waves).
// ---------------------------------------------------------------------------
__global__ __launch_bounds__(256) void k_pre(
    const float* __restrict__ feat, const float* __restrict__ hid,
    const float* __restrict__ Ww,   const float* __restrict__ bw,
    float* __restrict__ pre_f, float* __restrict__ pre_w)
{
    const int lane = threadIdx.x & 63;
    const int wave = threadIdx.x >> 6;
    const int row  = blockIdx.x * 4 + wave;       // 0..2999
    if (row >= F_N + JN) return;

    const float* emb;
    const float* W;
    float*       outp;
    float        acc = 0.0f;

    if (row < F_N) {                 // pre_f row
        emb  = feat + (size_t)row * D_N;
        W    = Ww;                   // W1 = Ww[0:64]
        outp = pre_f + (size_t)row * A_N;
        acc  = bw[lane];             // fold bias in here
    } else {                         // pre_w row
        const int j = row - F_N;
        emb  = (j < F_N) ? (feat + (size_t)j * D_N)
                         : (hid + (size_t)(j - F_N) * D_N);
        W    = Ww + D_N * A_N;       // W2 = Ww[64:128]
        outp = pre_w + (size_t)j * A_N;
    }

    const float e = emb[lane];       // one element per lane, broadcast by shfl
    #pragma unroll 16
    for (int d = 0; d < D_N; ++d) {
        const float w = W[d * A_N + lane];   // coalesced across lanes
        const float b = __shfl(e, d, 64);    // emb[row][d] broadcast
        acc = fmaf(b, w, acc);
    }
    outp[lane] = acc;
}

// ---------------------------------------------------------------------------
// Kernel 2: per i (block), scores over j, softmax-normalized context.
//   s(i,j)  = sum_a tanh(pre_f[i][a] + pre_w[j][a]) * Wu[a]
//   e(i,j)  = mask[i][j] ? exp(s) : 0
//   ctx[i]  = sum_j e * full[j] / sum_j e
// 500 blocks x 256 threads (4 waves). Lane = a dimension.
// Mask chunked 64-wide per wave, __ballot -> iterate only set bits
// (wave-uniform, no divergence). 2-way bit unroll for ILP.
// ---------------------------------------------------------------------------
__global__ __launch_bounds__(256) void k_attn(
    const float* __restrict__ feat, const float* __restrict__ hid,
    const float* __restrict__ pre_f, const float* __restrict__ pre_w,
    const float* __restrict__ Wu,   const void* __restrict__ mask,
    float* __restrict__ ctx)
{
    const int lane = threadIdx.x & 63;
    const int wave = threadIdx.x >> 6;
    const int i    = blockIdx.x;

    // --- runtime mask-dtype detection: bool bytes vs int32 -----------------
    // If int32 with 0/1 values, every u32 word <= 1. If byte-packed bools,
    // some of the first 256 words exceeds 1 with probability ~1 - 0.73^256.
    const uint32_t* mw = (const uint32_t*)mask;
    const uint32_t probe = mw[lane] | mw[64 + lane] | mw[128 + lane] | mw[192 + lane];
    const bool byteMode = (__ballot(probe > 1u) != 0ull);

    const float pf = pre_f[(size_t)i * A_N + lane];
    const float wu = Wu[lane];

    const uint8_t*  mb = (const uint8_t*)mask + (size_t)i * JN;
    const uint32_t* mi = (const uint32_t*)mask + (size_t)i * JN;

    float cacc = 0.0f;   // context partial (per lane = dim d)
    float sacc = 0.0f;   // score sum partial (lane-uniform)

    // 2500 j's -> 40 chunks of 64; wave w takes chunks w, w+4, ...
    for (int c = wave; c < 40; c += 4) {
        const int j0 = c * 64;
        const int j  = j0 + lane;
        uint32_t m = 0;
        if (j < JN) m = byteMode ? (uint32_t)mb[j] : mi[j];
        unsigned long long act = __ballot(m != 0);

        while (act) {
            const int b0 = __builtin_ctzll(act); act &= act - 1;
            const bool has1 = (act != 0ull);
            const int b1 = has1 ? __builtin_ctzll(act) : b0;
            if (has1) act &= act - 1;
            const int jj0 = j0 + b0;
            const int jj1 = j0 + b1;

            const float x0 = pf + pre_w[(size_t)jj0 * A_N + lane];
            const float x1 = pf + pre_w[(size_t)jj1 * A_N + lane];
            // tanh(x) = 1 - 2/(exp(2x)+1); safe for all x (no inf/inf)
            const float t0 = 1.0f - 2.0f / (__expf(2.0f * x0) + 1.0f);
            const float t1 = 1.0f - 2.0f / (__expf(2.0f * x1) + 1.0f);
            float p0 = t0 * wu;
            float p1 = t1 * wu;
            #pragma unroll
            for (int off = 1; off < 64; off <<= 1) {
                p0 += __shfl_xor(p0, off, 64);
                p1 += __shfl_xor(p1, off, 64);
            }
            const float e0 = __expf(p0);
            const float e1 = has1 ? __expf(p1) : 0.0f;
            sacc += e0 + e1;

            const float f0 = (jj0 < F_N) ? feat[(size_t)jj0 * D_N + lane]
                                         : hid[(size_t)(jj0 - F_N) * D_N + lane];
            const float f1 = (jj1 < F_N) ? feat[(size_t)jj1 * D_N + lane]
                                         : hid[(size_t)(jj1 - F_N) * D_N + lane];
            cacc = fmaf(e0, f0, cacc);
            cacc = fmaf(e1, f1, cacc);
        }
    }

    __shared__ float s_ctx[4][64];
    __shared__ float s_sum[4];
    s_ctx[wave][lane] = cacc;
    if (lane == 0) s_sum[wave] = sacc;
    __syncthreads();
    if (wave == 0) {
        const float c4 = s_ctx[0][lane] + s_ctx[1][lane] + s_ctx[2][lane] + s_ctx[3][lane];
        float s = s_sum[0] + s_sum[1] + s_sum[2] + s_sum[3];
        if (s == 0.0f) s = 1.0f;     // reference: where(ssum==0, 1, ssum)
        ctx[(size_t)i * D_N + lane] = c4 / s;
    }
}

// ---------------------------------------------------------------------------
// Kernel 3: out = values (4096x500) @ ctx (500x64), f32 VALU.
// 512 blocks x 256 threads; block handles 8 rows (2 rows per wave), lane = d.
// ctx staged in LDS in 100-k chunks (25.6 KB); values rows read as float4
// (row stride 2000 B and chunk offsets 400 B are 16B-aligned).
// ---------------------------------------------------------------------------
__global__ __launch_bounds__(256) void k_out(
    const float* __restrict__ values, const float* __restrict__ ctx,
    float* __restrict__ out)
{
    const int lane = threadIdx.x & 63;
    const int wave = threadIdx.x >> 6;
    const int row0 = blockIdx.x * 8 + wave * 2;   // 2 consecutive rows per wave

    __shared__ float lds[100 * 64];
    float acc0 = 0.0f, acc1 = 0.0f;

    for (int chunk = 0; chunk < 5; ++chunk) {
        const int k0 = chunk * 100;
        __syncthreads();
        for (int t = threadIdx.x; t < 100 * 64; t += 256)
            lds[t] = ctx[(size_t)k0 * 64 + t];
        __syncthreads();

        const float* v0p = values + (size_t)row0 * 500 + k0;
        const float* v1p = v0p + 500;
        #pragma unroll 5
        for (int kc = 0; kc < 100; kc += 4) {
            const float4 a = *(const float4*)(v0p + kc);
            const float4 b = *(const float4*)(v1p + kc);
            const float l0 = lds[(kc + 0) * 64 + lane];
            const float l1 = lds[(kc + 1) * 64 + lane];
            const float l2 = lds[(kc + 2) * 64 + lane];
            const float l3 = lds[(kc + 3) * 64 + lane];
            acc0 = fmaf(a.x, l0, acc0); acc0 = fmaf(a.y, l1, acc0);
            acc0 = fmaf(a.z, l2, acc0); acc0 = fmaf(a.w, l3, acc0);
            acc1 = fmaf(b.x, l0, acc1); acc1 = fmaf(b.y, l1, acc1);
            acc1 = fmaf(b.z, l2, acc1); acc1 = fmaf(b.w, l3, acc1);
        }
    }
    out[(size_t)row0 * 64 + lane]       = acc0;
    out[(size_t)(row0 + 1) * 64 + lane] = acc1;
}

// ---------------------------------------------------------------------------
extern "C" void kernel_launch(void* const* d_in, const int* in_sizes, int n_in,
                              void* d_out, int out_size, void* d_ws, size_t ws_size,
                              hipStream_t stream)
{
    const float* values = (const float*)d_in[0];   // (4096, 500)
    const float* feat   = (const float*)d_in[1];   // (500, 64)
    const float* hid    = (const float*)d_in[2];   // (2000, 64)
    const float* Ww     = (const float*)d_in[3];   // (128, 64)
    const float* bw     = (const float*)d_in[4];   // (64,)
    const float* Wu     = (const float*)d_in[5];   // (64, 1)
    const void*  mask   = d_in[6];                 // (500, 2500, 1) bool — dtype detected on device
    float* out = (float*)d_out;                    // (4096, 64)

    // Workspace layout (floats): pre_f[500*64] | pre_w[2500*64] | ctx[500*64]
    float* wsf   = (float*)d_ws;
    float* pre_f = wsf;                  // 32000 floats
    float* pre_w = wsf + 32000;          // 160000 floats
    float* ctx   = wsf + 192000;         // 32000 floats   (total 896 KB)

    k_pre <<<750, 256, 0, stream>>>(feat, hid, Ww, bw, pre_f, pre_w);
    k_attn<<<500, 256, 0, stream>>>(feat, hid, pre_f, pre_w, Wu, mask, ctx);
    k_out <<<512, 256, 0, stream>>>(values, ctx, out);
}